// Round 7
// baseline (4835.555 us; speedup 1.0000x reference)
//
#include <hip/hip_runtime.h>
#include <math.h>

#define FEAT 1024
#define NB 16       // batch
#define NT 256      // seq len
#define VOCAB 32000
#define G3 3072     // 3*FEAT
#define NWG 256     // scan workgroups

#define BK 32       // K-step of the MFMA GEMM
#define LDH 40      // f16 row stride in LDS

typedef float f4 __attribute__((ext_vector_type(4)));
typedef float f32x4 __attribute__((ext_vector_type(4)));
typedef unsigned u4 __attribute__((ext_vector_type(4)));
typedef _Float16 half4v __attribute__((ext_vector_type(4)));
typedef _Float16 half8v __attribute__((ext_vector_type(8)));

// ---------------- embedding gather: xs[t*NB+b][:] = emb[x[b][t]] ----------------
__global__ __launch_bounds__(256) void gather_kernel(const int* __restrict__ x,
                                                     const float* __restrict__ emb,
                                                     float* __restrict__ xs) {
    int row = blockIdx.x;
    int t = row >> 4;
    int b = row & 15;
    int tok = x[b * NT + t];
    const float4* src = (const float4*)(emb + (size_t)tok * FEAT);
    float4* dst = (float4*)(xs + (size_t)row * FEAT);
    dst[threadIdx.x] = src[threadIdx.x];
}

// ---------------- split-f16 MFMA GEMM (unchanged from round 6, passing) ----------
__global__ __launch_bounds__(256, 2) void gemm_split16(
        const float* __restrict__ A, const float* __restrict__ Bm,
        const float* __restrict__ bias, float* __restrict__ C,
        int M, int N, int K, int GM, int perm) {
    __shared__ _Float16 AhS[128 * LDH];
    __shared__ _Float16 AlS[128 * LDH];
    __shared__ _Float16 BhS[128 * LDH];
    __shared__ _Float16 BlS[128 * LDH];

    int nNt = N >> 7;
    int perGroup = GM * nNt;
    int g = blockIdx.x / perGroup;
    int rix = blockIdx.x % perGroup;
    int n_t = rix / GM;
    int m_t = g * GM + (rix % GM);

    int tid = threadIdx.x;
    int srow = tid >> 1;
    int shf = tid & 1;

    const float* aptr = A + (size_t)(m_t * 128 + srow) * K + shf * 16;
    const float* bptr = Bm + (size_t)(n_t * 128 + srow) * K + shf * 16;

    int wid = tid >> 6;
    int wr = wid >> 1, wc = wid & 1;
    int lane = tid & 63;
    int fr = lane & 15;
    int ke = lane >> 4;

    f32x4 acc[4][4];
#pragma unroll
    for (int i = 0; i < 4; i++)
#pragma unroll
        for (int j = 0; j < 4; j++) acc[i][j] = (f32x4){0.f, 0.f, 0.f, 0.f};

    float4 a4[4], b4[4];
#pragma unroll
    for (int q = 0; q < 4; q++) {
        a4[q] = *(const float4*)(aptr + q * 4);
        b4[q] = *(const float4*)(bptr + q * 4);
    }

    for (int k0 = 0; k0 < K; k0 += BK) {
        __syncthreads();
#pragma unroll
        for (int q = 0; q < 4; q++) {
            half4v hh, hl;
            hh.x = (_Float16)a4[q].x; hl.x = (_Float16)(a4[q].x - (float)hh.x);
            hh.y = (_Float16)a4[q].y; hl.y = (_Float16)(a4[q].y - (float)hh.y);
            hh.z = (_Float16)a4[q].z; hl.z = (_Float16)(a4[q].z - (float)hh.z);
            hh.w = (_Float16)a4[q].w; hl.w = (_Float16)(a4[q].w - (float)hh.w);
            int o = srow * LDH + shf * 16 + q * 4;
            *(half4v*)&AhS[o] = hh;
            *(half4v*)&AlS[o] = hl;
            half4v gh, gl;
            gh.x = (_Float16)b4[q].x; gl.x = (_Float16)(b4[q].x - (float)gh.x);
            gh.y = (_Float16)b4[q].y; gl.y = (_Float16)(b4[q].y - (float)gh.y);
            gh.z = (_Float16)b4[q].z; gl.z = (_Float16)(b4[q].z - (float)gh.z);
            gh.w = (_Float16)b4[q].w; gl.w = (_Float16)(b4[q].w - (float)gh.w);
            *(half4v*)&BhS[o] = gh;
            *(half4v*)&BlS[o] = gl;
        }
        __syncthreads();

        if (k0 + BK < K) {
#pragma unroll
            for (int q = 0; q < 4; q++) {
                a4[q] = *(const float4*)(aptr + k0 + BK + q * 4);
                b4[q] = *(const float4*)(bptr + k0 + BK + q * 4);
            }
        }

        half8v ah[4], al[4], bh[4], bl[4];
#pragma unroll
        for (int i = 0; i < 4; i++) {
            int ao = (wr * 64 + i * 16 + fr) * LDH + ke * 8;
            ah[i] = *(const half8v*)&AhS[ao];
            al[i] = *(const half8v*)&AlS[ao];
            int bo = (wc * 64 + i * 16 + fr) * LDH + ke * 8;
            bh[i] = *(const half8v*)&BhS[bo];
            bl[i] = *(const half8v*)&BlS[bo];
        }
#pragma unroll
        for (int i = 0; i < 4; i++)
#pragma unroll
            for (int j = 0; j < 4; j++) {
                acc[i][j] = __builtin_amdgcn_mfma_f32_16x16x32_f16(ah[i], bh[j], acc[i][j], 0, 0, 0);
                acc[i][j] = __builtin_amdgcn_mfma_f32_16x16x32_f16(ah[i], bl[j], acc[i][j], 0, 0, 0);
                acc[i][j] = __builtin_amdgcn_mfma_f32_16x16x32_f16(al[i], bh[j], acc[i][j], 0, 0, 0);
            }
    }

#pragma unroll
    for (int j = 0; j < 4; j++) {
        int col = n_t * 128 + wc * 64 + j * 16 + fr;
        float bv = bias[col];
#pragma unroll
        for (int i = 0; i < 4; i++) {
#pragma unroll
            for (int v = 0; v < 4; v++) {
                int mrow = m_t * 128 + wr * 64 + i * 16 + 4 * ke + v;
                int orow = perm ? (((mrow & 15) << 8) | (mrow >> 4)) : mrow;
                C[(size_t)orow * N + col] = acc[i][j][v] + bv;
            }
        }
    }
}

// ---------------- agent-coherent store (bypass non-coherent L2, hit LLC) --------
__device__ __forceinline__ void store_f32_sc(float* p, float v) {
    asm volatile("global_store_dword %0, %1, off sc0 sc1" :: "v"(p), "v"(v) : "memory");
}

// ---------------- persistent GRU scan (one layer) ----------------
// 256 WGs x 256 threads, 1 block/CU (100KB LDS). WG wg owns cols [wg*4, wg*4+4).
// Thread (bg = tid>>6, kc = tid&63): 4 batches x 16 k-floats; each W ds_read
// amortized over 4 batches (48 b128 reads/step vs 192 in round 6).
// Barrier: single-hop all-poll — arrive via 1 sc1 store; every thread polls 4
// flags with one dwordx4 sc1 load and proceeds as soon as all are set.
__global__ __launch_bounds__(256, 1) void gru_scan(const float* __restrict__ xp,
                                                   const float* __restrict__ Whh,
                                                   const float* __restrict__ bhh,
                                                   const float* __restrict__ h0src,
                                                   float* __restrict__ ys,
                                                   float* __restrict__ buf0,
                                                   float* __restrict__ buf1,
                                                   float* __restrict__ hid,
                                                   unsigned* __restrict__ flags,
                                                   unsigned gen_base) {
    __shared__ float w_lds[12 * 1028];      // 48.2 KB
    __shared__ float red[192 * 65];         // 49.9 KB, [o][kc] lane-consecutive
    __shared__ float sum_lds[192];
    __shared__ float bhh_lds[12];

    int wg = blockIdx.x;
    int j0 = wg * 4;
    int tid = threadIdx.x;

    // stage the 12 W_hh rows for this WG into LDS (coalesced float4)
    for (int rr = 0; rr < 12; rr++) {
        int gate = rr >> 2, jloc = rr & 3;
        int grow = gate * FEAT + j0 + jloc;
        float4 v = ((const float4*)(Whh + (size_t)grow * FEAT))[tid];
        *(float4*)(w_lds + rr * 1028 + tid * 4) = v;
    }
    if (tid < 12) {
        int gate = tid >> 2, jloc = tid & 3;
        bhh_lds[tid] = bhh[gate * FEAT + j0 + jloc];
    }
    __syncthreads();

    int bg = tid >> 6;        // 0..3 : batch group (4 batches)
    int kc = tid & 63;        // 0..63 : k base kc*4, q-strided by 256
    int pb = tid >> 2, pjl = tid & 3, pj = j0 + pjl;   // gating map (tid<64)

    // prologue xp prefetch for t=0
    float xr = 0.f, xz = 0.f, xnv = 0.f;
    if (tid < 64) {
        const float* xpr = xp + (size_t)(0 * NB + pb) * G3;
        xr = xpr[pj]; xz = xpr[FEAT + pj]; xnv = xpr[2 * FEAT + pj];
    }

    for (int t = 0; t < NT; t++) {
        const float* hc = (t == 0) ? h0src : ((t & 1) ? buf0 : buf1);
        float* hn = (t & 1) ? buf1 : buf0;

        float hold = 0.f;
        if (tid < 64) {
            asm volatile("global_load_dword %0, %1, off sc0 sc1"
                         : "=&v"(hold) : "v"(hc + pb * FEAT + pj) : "memory");
        }

        // ---- coherent h load: 4 batches x 4 q-chunks, lane-contiguous 16B ----
        f4 h4[16];   // h4[bi*4+q]
        {
            const float* p0 = hc + (bg * 4 + 0) * FEAT + kc * 4;
            const float* p1 = hc + (bg * 4 + 1) * FEAT + kc * 4;
            const float* p2 = hc + (bg * 4 + 2) * FEAT + kc * 4;
            const float* p3 = hc + (bg * 4 + 3) * FEAT + kc * 4;
            asm volatile(
                "global_load_dwordx4 %0,  %16, off sc0 sc1\n\t"
                "global_load_dwordx4 %1,  %16, off offset:1024 sc0 sc1\n\t"
                "global_load_dwordx4 %2,  %16, off offset:2048 sc0 sc1\n\t"
                "global_load_dwordx4 %3,  %16, off offset:3072 sc0 sc1\n\t"
                "global_load_dwordx4 %4,  %17, off sc0 sc1\n\t"
                "global_load_dwordx4 %5,  %17, off offset:1024 sc0 sc1\n\t"
                "global_load_dwordx4 %6,  %17, off offset:2048 sc0 sc1\n\t"
                "global_load_dwordx4 %7,  %17, off offset:3072 sc0 sc1\n\t"
                "global_load_dwordx4 %8,  %18, off sc0 sc1\n\t"
                "global_load_dwordx4 %9,  %18, off offset:1024 sc0 sc1\n\t"
                "global_load_dwordx4 %10, %18, off offset:2048 sc0 sc1\n\t"
                "global_load_dwordx4 %11, %18, off offset:3072 sc0 sc1\n\t"
                "global_load_dwordx4 %12, %19, off sc0 sc1\n\t"
                "global_load_dwordx4 %13, %19, off offset:1024 sc0 sc1\n\t"
                "global_load_dwordx4 %14, %19, off offset:2048 sc0 sc1\n\t"
                "global_load_dwordx4 %15, %19, off offset:3072 sc0 sc1\n\t"
                "s_waitcnt vmcnt(0)"
                : "=&v"(h4[0]), "=&v"(h4[1]), "=&v"(h4[2]), "=&v"(h4[3]),
                  "=&v"(h4[4]), "=&v"(h4[5]), "=&v"(h4[6]), "=&v"(h4[7]),
                  "=&v"(h4[8]), "=&v"(h4[9]), "=&v"(h4[10]), "=&v"(h4[11]),
                  "=&v"(h4[12]), "=&v"(h4[13]), "=&v"(h4[14]), "=&v"(h4[15])
                : "v"(p0), "v"(p1), "v"(p2), "v"(p3) : "memory");
            __builtin_amdgcn_sched_barrier(0);
        }

        // ---- 12 rows x 4 batches partials; W read once per (q,row) ----
        float part[48];
#pragma unroll
        for (int i = 0; i < 48; i++) part[i] = 0.f;
#pragma unroll
        for (int q = 0; q < 4; q++) {
            int kof = q * 256 + kc * 4;
#pragma unroll
            for (int rr = 0; rr < 12; rr++) {
                f4 w = *(const f4*)&w_lds[rr * 1028 + kof];
#pragma unroll
                for (int bi = 0; bi < 4; bi++) {
                    part[rr * 4 + bi] = fmaf(h4[bi * 4 + q].x, w.x, part[rr * 4 + bi]);
                    part[rr * 4 + bi] = fmaf(h4[bi * 4 + q].y, w.y, part[rr * 4 + bi]);
                    part[rr * 4 + bi] = fmaf(h4[bi * 4 + q].z, w.z, part[rr * 4 + bi]);
                    part[rr * 4 + bi] = fmaf(h4[bi * 4 + q].w, w.w, part[rr * 4 + bi]);
                }
            }
        }
#pragma unroll
        for (int rr = 0; rr < 12; rr++)
#pragma unroll
            for (int bi = 0; bi < 4; bi++)
                red[(rr * 16 + bg * 4 + bi) * 65 + kc] = part[rr * 4 + bi];
        __syncthreads();

        if (tid < 192) {
            float s = 0.f;
#pragma unroll
            for (int q = 0; q < 64; q++) s += red[tid * 65 + q];
            sum_lds[tid] = s;
        }
        __syncthreads();

        if (tid < 64) {
            float dr = sum_lds[pjl * 16 + pb] + bhh_lds[pjl];
            float dz = sum_lds[(4 + pjl) * 16 + pb] + bhh_lds[4 + pjl];
            float dn = sum_lds[(8 + pjl) * 16 + pb] + bhh_lds[8 + pjl];
            float r = 1.f / (1.f + expf(-(xr + dr)));
            float z = 1.f / (1.f + expf(-(xz + dz)));
            float n = tanhf(xnv + r * dn);
            float hv = (1.f - z) * n + z * hold;
            store_f32_sc(hn + pb * FEAT + pj, hv);       // coherent h publish
            ys[(size_t)(t * NB + pb) * FEAT + pj] = hv;  // plain (next kernel)
            if (t == NT - 1) hid[pb * FEAT + pj] = hv;
            // prefetch xp for t+1 (latency hides in the barrier wait)
            int tn = (t + 1 < NT) ? t + 1 : t;
            const float* xpr = xp + (size_t)(tn * NB + pb) * G3;
            xr = xpr[pj]; xz = xpr[FEAT + pj]; xnv = xpr[2 * FEAT + pj];
        }

        // ---- single-hop all-poll barrier ----
        __syncthreads();                 // drains gating waves' sc1 h-stores
        unsigned expected = gen_base + t + 1;
        if (tid == 0) {
            asm volatile("s_waitcnt vmcnt(0)\n\t"
                         "global_store_dword %0, %1, off sc0 sc1"
                         :: "v"(&flags[wg]), "v"(expected) : "memory");
        }
        {
            const unsigned* fp = flags + 4 * (tid & 63);
            u4 v; int spins = 0;
            while (true) {
                asm volatile("global_load_dwordx4 %0, %1, off sc0 sc1\n\t"
                             "s_waitcnt vmcnt(0)"
                             : "=&v"(v) : "v"(fp) : "memory");
                if (v.x >= expected && v.y >= expected &&
                    v.z >= expected && v.w >= expected) break;
                if (++spins > (1 << 20)) break;   // safety valve
                __builtin_amdgcn_s_sleep(1);
            }
            __builtin_amdgcn_sched_barrier(0);
        }
        // no __syncthreads: each thread verified all 256 flags itself
    }
}

// ---------------- launcher ----------------
extern "C" void kernel_launch(void* const* d_in, const int* in_sizes, int n_in,
                              void* d_out, int out_size, void* d_ws, size_t ws_size,
                              hipStream_t stream) {
    const int*   x     = (const int*)d_in[0];
    const float* h0    = (const float*)d_in[1];
    const float* emb   = (const float*)d_in[2];
    const float* W_ih0 = (const float*)d_in[3];
    const float* W_hh0 = (const float*)d_in[4];
    const float* b_ih0 = (const float*)d_in[5];
    const float* b_hh0 = (const float*)d_in[6];
    const float* W_ih1 = (const float*)d_in[7];
    const float* W_hh1 = (const float*)d_in[8];
    const float* b_ih1 = (const float*)d_in[9];
    const float* b_hh1 = (const float*)d_in[10];
    const float* dec_b = (const float*)d_in[11];

    float* out = (float*)d_out;
    float* hid_out = out + (size_t)NB * NT * VOCAB;

    float* ws  = (float*)d_ws;
    float* xp  = ws;                                    // [4096][3072]
    float* xs  = xp + (size_t)4096 * 3072;              // [4096][1024] (also ys1)
    float* ys0 = xs + (size_t)4096 * 1024;              // [4096][1024]
    float* ha  = ys0 + (size_t)4096 * 1024;             // [16][1024]
    float* hb  = ha + NB * FEAT;                        // [16][1024]
    unsigned* flags = (unsigned*)(hb + NB * FEAT);      // 256 uints, 16B-aligned
    float* ys1 = xs;                                    // reuse (xs dead after xp0)

    // 0. zero the barrier flags
    hipMemsetAsync((void*)flags, 0, 512 * sizeof(unsigned), stream);

    // 1. gather
    gather_kernel<<<dim3(NT * NB), dim3(256), 0, stream>>>(x, emb, xs);

    // 2. x_proj layer 0 (split-f16 MFMA)
    gemm_split16<<<dim3((4096 / 128) * (G3 / 128)), dim3(256), 0, stream>>>(
        xs, W_ih0, b_ih0, xp, 4096, G3, FEAT, 8, 0);

    // 3. scan layer 0 (gens 1..256)
    gru_scan<<<dim3(NWG), dim3(256), 0, stream>>>(
        xp, W_hh0, b_hh0, h0, ys0, ha, hb, hid_out, flags, 0u);

    // 4. x_proj layer 1
    gemm_split16<<<dim3((4096 / 128) * (G3 / 128)), dim3(256), 0, stream>>>(
        ys0, W_ih1, b_ih1, xp, 4096, G3, FEAT, 8, 0);

    // 5. scan layer 1 (gens 257..512)
    gru_scan<<<dim3(NWG), dim3(256), 0, stream>>>(
        xp, W_hh1, b_hh1, h0 + NB * FEAT, ys1, ha, hb, hid_out + NB * FEAT,
        flags, (unsigned)NT);

    // 6. tied decoder (split-f16 MFMA, perm on C-write)
    gemm_split16<<<dim3((4096 / 128) * (VOCAB / 128)), dim3(256), 0, stream>>>(
        ys1, emb, dec_b, out, 4096, VOCAB, FEAT, 8, 1);
}

// Round 8
// 3685.616 us; speedup vs baseline: 1.3120x; 1.3120x over previous
//
#include <hip/hip_runtime.h>
#include <math.h>

#define FEAT 1024
#define NB 16       // batch
#define NT 256      // seq len
#define VOCAB 32000
#define G3 3072     // 3*FEAT
#define NWG 256     // scan workgroups
#define FLAG_STRIDE 32   // 128B between flags -> spread across LLC slices

#define BK 32       // K-step of the MFMA GEMM
#define LDH 40      // f16 row stride in LDS

typedef float f4 __attribute__((ext_vector_type(4)));
typedef float f32x4 __attribute__((ext_vector_type(4)));
typedef _Float16 half4v __attribute__((ext_vector_type(4)));
typedef _Float16 half8v __attribute__((ext_vector_type(8)));

// ---------------- embedding gather: xs[t*NB+b][:] = emb[x[b][t]] ----------------
__global__ __launch_bounds__(256) void gather_kernel(const int* __restrict__ x,
                                                     const float* __restrict__ emb,
                                                     float* __restrict__ xs) {
    int row = blockIdx.x;
    int t = row >> 4;
    int b = row & 15;
    int tok = x[b * NT + t];
    const float4* src = (const float4*)(emb + (size_t)tok * FEAT);
    float4* dst = (float4*)(xs + (size_t)row * FEAT);
    dst[threadIdx.x] = src[threadIdx.x];
}

// ---------------- split-f16 MFMA GEMM (unchanged, passing since round 6) --------
__global__ __launch_bounds__(256, 2) void gemm_split16(
        const float* __restrict__ A, const float* __restrict__ Bm,
        const float* __restrict__ bias, float* __restrict__ C,
        int M, int N, int K, int GM, int perm) {
    __shared__ _Float16 AhS[128 * LDH];
    __shared__ _Float16 AlS[128 * LDH];
    __shared__ _Float16 BhS[128 * LDH];
    __shared__ _Float16 BlS[128 * LDH];

    int nNt = N >> 7;
    int perGroup = GM * nNt;
    int g = blockIdx.x / perGroup;
    int rix = blockIdx.x % perGroup;
    int n_t = rix / GM;
    int m_t = g * GM + (rix % GM);

    int tid = threadIdx.x;
    int srow = tid >> 1;
    int shf = tid & 1;

    const float* aptr = A + (size_t)(m_t * 128 + srow) * K + shf * 16;
    const float* bptr = Bm + (size_t)(n_t * 128 + srow) * K + shf * 16;

    int wid = tid >> 6;
    int wr = wid >> 1, wc = wid & 1;
    int lane = tid & 63;
    int fr = lane & 15;
    int ke = lane >> 4;

    f32x4 acc[4][4];
#pragma unroll
    for (int i = 0; i < 4; i++)
#pragma unroll
        for (int j = 0; j < 4; j++) acc[i][j] = (f32x4){0.f, 0.f, 0.f, 0.f};

    float4 a4[4], b4[4];
#pragma unroll
    for (int q = 0; q < 4; q++) {
        a4[q] = *(const float4*)(aptr + q * 4);
        b4[q] = *(const float4*)(bptr + q * 4);
    }

    for (int k0 = 0; k0 < K; k0 += BK) {
        __syncthreads();
#pragma unroll
        for (int q = 0; q < 4; q++) {
            half4v hh, hl;
            hh.x = (_Float16)a4[q].x; hl.x = (_Float16)(a4[q].x - (float)hh.x);
            hh.y = (_Float16)a4[q].y; hl.y = (_Float16)(a4[q].y - (float)hh.y);
            hh.z = (_Float16)a4[q].z; hl.z = (_Float16)(a4[q].z - (float)hh.z);
            hh.w = (_Float16)a4[q].w; hl.w = (_Float16)(a4[q].w - (float)hh.w);
            int o = srow * LDH + shf * 16 + q * 4;
            *(half4v*)&AhS[o] = hh;
            *(half4v*)&AlS[o] = hl;
            half4v gh, gl;
            gh.x = (_Float16)b4[q].x; gl.x = (_Float16)(b4[q].x - (float)gh.x);
            gh.y = (_Float16)b4[q].y; gl.y = (_Float16)(b4[q].y - (float)gh.y);
            gh.z = (_Float16)b4[q].z; gl.z = (_Float16)(b4[q].z - (float)gh.z);
            gh.w = (_Float16)b4[q].w; gl.w = (_Float16)(b4[q].w - (float)gh.w);
            *(half4v*)&BhS[o] = gh;
            *(half4v*)&BlS[o] = gl;
        }
        __syncthreads();

        if (k0 + BK < K) {
#pragma unroll
            for (int q = 0; q < 4; q++) {
                a4[q] = *(const float4*)(aptr + k0 + BK + q * 4);
                b4[q] = *(const float4*)(bptr + k0 + BK + q * 4);
            }
        }

        half8v ah[4], al[4], bh[4], bl[4];
#pragma unroll
        for (int i = 0; i < 4; i++) {
            int ao = (wr * 64 + i * 16 + fr) * LDH + ke * 8;
            ah[i] = *(const half8v*)&AhS[ao];
            al[i] = *(const half8v*)&AlS[ao];
            int bo = (wc * 64 + i * 16 + fr) * LDH + ke * 8;
            bh[i] = *(const half8v*)&BhS[bo];
            bl[i] = *(const half8v*)&BlS[bo];
        }
#pragma unroll
        for (int i = 0; i < 4; i++)
#pragma unroll
            for (int j = 0; j < 4; j++) {
                acc[i][j] = __builtin_amdgcn_mfma_f32_16x16x32_f16(ah[i], bh[j], acc[i][j], 0, 0, 0);
                acc[i][j] = __builtin_amdgcn_mfma_f32_16x16x32_f16(ah[i], bl[j], acc[i][j], 0, 0, 0);
                acc[i][j] = __builtin_amdgcn_mfma_f32_16x16x32_f16(al[i], bh[j], acc[i][j], 0, 0, 0);
            }
    }

#pragma unroll
    for (int j = 0; j < 4; j++) {
        int col = n_t * 128 + wc * 64 + j * 16 + fr;
        float bv = bias[col];
#pragma unroll
        for (int i = 0; i < 4; i++) {
#pragma unroll
            for (int v = 0; v < 4; v++) {
                int mrow = m_t * 128 + wr * 64 + i * 16 + 4 * ke + v;
                int orow = perm ? (((mrow & 15) << 8) | (mrow >> 4)) : mrow;
                C[(size_t)orow * N + col] = acc[i][j][v] + bv;
            }
        }
    }
}

// ---------------- agent-coherent store (bypass non-coherent L2, hit LLC) --------
__device__ __forceinline__ void store_f32_sc(float* p, float v) {
    asm volatile("global_store_dword %0, %1, off sc0 sc1" :: "v"(p), "v"(v) : "memory");
}

// ---------------- single-hop, wave-0-poll, spread-flag grid barrier ----------------
// Arrive: 1 sc1 dword store to a private 128B-spaced flag (256 lines, slice-spread).
// Detect: wave 0 only — lane l polls 4 spread flags with 4 scalar sc1 dwords.
// Release: __syncthreads. One LLC hop total; poll traffic 4x lower than round 7
// and spread over 256 lines instead of 8 (the round-7 slice-contention bug).
__device__ __forceinline__ void grid_barrier5(unsigned* __restrict__ flags,
                                              unsigned expected, int wg, int tid) {
    __syncthreads();                    // all waves' sc1 h-stores drained
    if (tid == 0) {
        asm volatile("s_waitcnt vmcnt(0)\n\t"
                     "global_store_dword %0, %1, off sc0 sc1"
                     :: "v"(&flags[wg * FLAG_STRIDE]), "v"(expected) : "memory");
    }
    if (tid < 64) {
        const unsigned* f0 = flags + (tid * 4 + 0) * FLAG_STRIDE;
        const unsigned* f1 = flags + (tid * 4 + 1) * FLAG_STRIDE;
        const unsigned* f2 = flags + (tid * 4 + 2) * FLAG_STRIDE;
        const unsigned* f3 = flags + (tid * 4 + 3) * FLAG_STRIDE;
        unsigned v0, v1, v2, v3;
        int spins = 0;
        while (true) {
            asm volatile(
                "global_load_dword %0, %4, off sc0 sc1\n\t"
                "global_load_dword %1, %5, off sc0 sc1\n\t"
                "global_load_dword %2, %6, off sc0 sc1\n\t"
                "global_load_dword %3, %7, off sc0 sc1\n\t"
                "s_waitcnt vmcnt(0)"
                : "=&v"(v0), "=&v"(v1), "=&v"(v2), "=&v"(v3)
                : "v"(f0), "v"(f1), "v"(f2), "v"(f3) : "memory");
            if (v0 >= expected && v1 >= expected &&
                v2 >= expected && v3 >= expected) break;
            if (++spins > (1 << 20)) break;   // safety valve
            __builtin_amdgcn_s_sleep(1);
        }
        __builtin_amdgcn_sched_barrier(0);
    }
    __syncthreads();                    // release waves 1-3
}

// ---------------- persistent GRU scan (one layer) ----------------
// 256 WGs x 256 threads, 1 block/CU (100KB LDS). WG wg owns cols [wg*4, wg*4+4).
// Thread (bg = tid>>6, kc = tid&63): 4 batches x 16 k-floats; 48 b128 ds_reads
// per step; conflict-free reduce layout red[o*65+kc].
__global__ __launch_bounds__(256, 1) void gru_scan(const float* __restrict__ xp,
                                                   const float* __restrict__ Whh,
                                                   const float* __restrict__ bhh,
                                                   const float* __restrict__ h0src,
                                                   float* __restrict__ ys,
                                                   float* __restrict__ buf0,
                                                   float* __restrict__ buf1,
                                                   float* __restrict__ hid,
                                                   unsigned* __restrict__ flags,
                                                   unsigned gen_base) {
    __shared__ float w_lds[12 * 1028];      // 48.2 KB
    __shared__ float red[192 * 65];         // 49.9 KB, [o][kc] lane-consecutive
    __shared__ float sum_lds[192];
    __shared__ float bhh_lds[12];

    int wg = blockIdx.x;
    int j0 = wg * 4;
    int tid = threadIdx.x;

    for (int rr = 0; rr < 12; rr++) {
        int gate = rr >> 2, jloc = rr & 3;
        int grow = gate * FEAT + j0 + jloc;
        float4 v = ((const float4*)(Whh + (size_t)grow * FEAT))[tid];
        *(float4*)(w_lds + rr * 1028 + tid * 4) = v;
    }
    if (tid < 12) {
        int gate = tid >> 2, jloc = tid & 3;
        bhh_lds[tid] = bhh[gate * FEAT + j0 + jloc];
    }
    __syncthreads();

    int bg = tid >> 6;        // 0..3 : batch group (4 batches)
    int kc = tid & 63;        // 0..63 : k base kc*4, q-strided by 256
    int pb = tid >> 2, pjl = tid & 3, pj = j0 + pjl;   // gating map (tid<64)

    float xr = 0.f, xz = 0.f, xnv = 0.f;
    if (tid < 64) {
        const float* xpr = xp + (size_t)(0 * NB + pb) * G3;
        xr = xpr[pj]; xz = xpr[FEAT + pj]; xnv = xpr[2 * FEAT + pj];
    }

    for (int t = 0; t < NT; t++) {
        const float* hc = (t == 0) ? h0src : ((t & 1) ? buf0 : buf1);
        float* hn = (t & 1) ? buf1 : buf0;

        float hold = 0.f;
        if (tid < 64) {
            asm volatile("global_load_dword %0, %1, off sc0 sc1"
                         : "=&v"(hold) : "v"(hc + pb * FEAT + pj) : "memory");
        }

        // ---- coherent h load: 4 batches x 4 q-chunks, lane-contiguous 16B ----
        f4 h4[16];   // h4[bi*4+q]
        {
            const float* p0 = hc + (bg * 4 + 0) * FEAT + kc * 4;
            const float* p1 = hc + (bg * 4 + 1) * FEAT + kc * 4;
            const float* p2 = hc + (bg * 4 + 2) * FEAT + kc * 4;
            const float* p3 = hc + (bg * 4 + 3) * FEAT + kc * 4;
            asm volatile(
                "global_load_dwordx4 %0,  %16, off sc0 sc1\n\t"
                "global_load_dwordx4 %1,  %16, off offset:1024 sc0 sc1\n\t"
                "global_load_dwordx4 %2,  %16, off offset:2048 sc0 sc1\n\t"
                "global_load_dwordx4 %3,  %16, off offset:3072 sc0 sc1\n\t"
                "global_load_dwordx4 %4,  %17, off sc0 sc1\n\t"
                "global_load_dwordx4 %5,  %17, off offset:1024 sc0 sc1\n\t"
                "global_load_dwordx4 %6,  %17, off offset:2048 sc0 sc1\n\t"
                "global_load_dwordx4 %7,  %17, off offset:3072 sc0 sc1\n\t"
                "global_load_dwordx4 %8,  %18, off sc0 sc1\n\t"
                "global_load_dwordx4 %9,  %18, off offset:1024 sc0 sc1\n\t"
                "global_load_dwordx4 %10, %18, off offset:2048 sc0 sc1\n\t"
                "global_load_dwordx4 %11, %18, off offset:3072 sc0 sc1\n\t"
                "global_load_dwordx4 %12, %19, off sc0 sc1\n\t"
                "global_load_dwordx4 %13, %19, off offset:1024 sc0 sc1\n\t"
                "global_load_dwordx4 %14, %19, off offset:2048 sc0 sc1\n\t"
                "global_load_dwordx4 %15, %19, off offset:3072 sc0 sc1\n\t"
                "s_waitcnt vmcnt(0)"
                : "=&v"(h4[0]), "=&v"(h4[1]), "=&v"(h4[2]), "=&v"(h4[3]),
                  "=&v"(h4[4]), "=&v"(h4[5]), "=&v"(h4[6]), "=&v"(h4[7]),
                  "=&v"(h4[8]), "=&v"(h4[9]), "=&v"(h4[10]), "=&v"(h4[11]),
                  "=&v"(h4[12]), "=&v"(h4[13]), "=&v"(h4[14]), "=&v"(h4[15])
                : "v"(p0), "v"(p1), "v"(p2), "v"(p3) : "memory");
            __builtin_amdgcn_sched_barrier(0);
        }

        // ---- 12 rows x 4 batches partials; W read once per (q,row) ----
        float part[48];
#pragma unroll
        for (int i = 0; i < 48; i++) part[i] = 0.f;
#pragma unroll
        for (int q = 0; q < 4; q++) {
            int kof = q * 256 + kc * 4;
#pragma unroll
            for (int rr = 0; rr < 12; rr++) {
                f4 w = *(const f4*)&w_lds[rr * 1028 + kof];
#pragma unroll
                for (int bi = 0; bi < 4; bi++) {
                    part[rr * 4 + bi] = fmaf(h4[bi * 4 + q].x, w.x, part[rr * 4 + bi]);
                    part[rr * 4 + bi] = fmaf(h4[bi * 4 + q].y, w.y, part[rr * 4 + bi]);
                    part[rr * 4 + bi] = fmaf(h4[bi * 4 + q].z, w.z, part[rr * 4 + bi]);
                    part[rr * 4 + bi] = fmaf(h4[bi * 4 + q].w, w.w, part[rr * 4 + bi]);
                }
            }
        }
#pragma unroll
        for (int rr = 0; rr < 12; rr++)
#pragma unroll
            for (int bi = 0; bi < 4; bi++)
                red[(rr * 16 + bg * 4 + bi) * 65 + kc] = part[rr * 4 + bi];
        __syncthreads();

        if (tid < 192) {
            float s = 0.f;
#pragma unroll
            for (int q = 0; q < 64; q++) s += red[tid * 65 + q];
            sum_lds[tid] = s;
        }
        __syncthreads();

        if (tid < 64) {
            float dr = sum_lds[pjl * 16 + pb] + bhh_lds[pjl];
            float dz = sum_lds[(4 + pjl) * 16 + pb] + bhh_lds[4 + pjl];
            float dn = sum_lds[(8 + pjl) * 16 + pb] + bhh_lds[8 + pjl];
            float r = 1.f / (1.f + expf(-(xr + dr)));
            float z = 1.f / (1.f + expf(-(xz + dz)));
            float n = tanhf(xnv + r * dn);
            float hv = (1.f - z) * n + z * hold;
            store_f32_sc(hn + pb * FEAT + pj, hv);       // coherent h publish
            ys[(size_t)(t * NB + pb) * FEAT + pj] = hv;  // plain (next kernel)
            if (t == NT - 1) hid[pb * FEAT + pj] = hv;
            int tn = (t + 1 < NT) ? t + 1 : t;
            const float* xpr = xp + (size_t)(tn * NB + pb) * G3;
            xr = xpr[pj]; xz = xpr[FEAT + pj]; xnv = xpr[2 * FEAT + pj];
        }

        grid_barrier5(flags, gen_base + t + 1, wg, tid);
    }
}

// ---------------- launcher ----------------
extern "C" void kernel_launch(void* const* d_in, const int* in_sizes, int n_in,
                              void* d_out, int out_size, void* d_ws, size_t ws_size,
                              hipStream_t stream) {
    const int*   x     = (const int*)d_in[0];
    const float* h0    = (const float*)d_in[1];
    const float* emb   = (const float*)d_in[2];
    const float* W_ih0 = (const float*)d_in[3];
    const float* W_hh0 = (const float*)d_in[4];
    const float* b_ih0 = (const float*)d_in[5];
    const float* b_hh0 = (const float*)d_in[6];
    const float* W_ih1 = (const float*)d_in[7];
    const float* W_hh1 = (const float*)d_in[8];
    const float* b_ih1 = (const float*)d_in[9];
    const float* b_hh1 = (const float*)d_in[10];
    const float* dec_b = (const float*)d_in[11];

    float* out = (float*)d_out;
    float* hid_out = out + (size_t)NB * NT * VOCAB;

    float* ws  = (float*)d_ws;
    float* xp  = ws;                                    // [4096][3072]
    float* xs  = xp + (size_t)4096 * 3072;              // [4096][1024] (also ys1)
    float* ys0 = xs + (size_t)4096 * 1024;              // [4096][1024]
    float* ha  = ys0 + (size_t)4096 * 1024;             // [16][1024]
    float* hb  = ha + NB * FEAT;                        // [16][1024]
    unsigned* flags = (unsigned*)(hb + NB * FEAT);      // 256 * 32 uints (128B apart)
    float* ys1 = xs;                                    // reuse (xs dead after xp0)

    // 0. zero the barrier flags (32KB)
    hipMemsetAsync((void*)flags, 0, NWG * FLAG_STRIDE * sizeof(unsigned), stream);

    // 1. gather
    gather_kernel<<<dim3(NT * NB), dim3(256), 0, stream>>>(x, emb, xs);

    // 2. x_proj layer 0 (split-f16 MFMA)
    gemm_split16<<<dim3((4096 / 128) * (G3 / 128)), dim3(256), 0, stream>>>(
        xs, W_ih0, b_ih0, xp, 4096, G3, FEAT, 8, 0);

    // 3. scan layer 0 (gens 1..256)
    gru_scan<<<dim3(NWG), dim3(256), 0, stream>>>(
        xp, W_hh0, b_hh0, h0, ys0, ha, hb, hid_out, flags, 0u);

    // 4. x_proj layer 1
    gemm_split16<<<dim3((4096 / 128) * (G3 / 128)), dim3(256), 0, stream>>>(
        ys0, W_ih1, b_ih1, xp, 4096, G3, FEAT, 8, 0);

    // 5. scan layer 1 (gens 257..512)
    gru_scan<<<dim3(NWG), dim3(256), 0, stream>>>(
        xp, W_hh1, b_hh1, h0 + NB * FEAT, ys1, ha, hb, hid_out + NB * FEAT,
        flags, (unsigned)NT);

    // 6. tied decoder (split-f16 MFMA, perm on C-write)
    gemm_split16<<<dim3((4096 / 128) * (VOCAB / 128)), dim3(256), 0, stream>>>(
        ys1, emb, dec_b, out, 4096, VOCAB, FEAT, 8, 1);
}

// Round 9
// 3598.667 us; speedup vs baseline: 1.3437x; 1.0242x over previous
//
#include <hip/hip_runtime.h>
#include <math.h>

#define FEAT 1024
#define NB 16       // batch
#define NT 256      // seq len
#define VOCAB 32000
#define G3 3072     // 3*FEAT
#define NWG 256     // scan workgroups
#define FLAG_STRIDE 32   // 128B between flags -> spread across LLC slices
#define NGRP 8      // barrier groups (leaders = blocks 0..7)
#define GSZ 32      // blocks per group

#define BK 32       // K-step of the MFMA GEMM
#define LDH 40      // f16 row stride in LDS

typedef float f4 __attribute__((ext_vector_type(4)));
typedef float f32x4 __attribute__((ext_vector_type(4)));
typedef _Float16 half4v __attribute__((ext_vector_type(4)));
typedef _Float16 half8v __attribute__((ext_vector_type(8)));

// ---------------- embedding gather: xs[t*NB+b][:] = emb[x[b][t]] ----------------
__global__ __launch_bounds__(256) void gather_kernel(const int* __restrict__ x,
                                                     const float* __restrict__ emb,
                                                     float* __restrict__ xs) {
    int row = blockIdx.x;
    int t = row >> 4;
    int b = row & 15;
    int tok = x[b * NT + t];
    const float4* src = (const float4*)(emb + (size_t)tok * FEAT);
    float4* dst = (float4*)(xs + (size_t)row * FEAT);
    dst[threadIdx.x] = src[threadIdx.x];
}

// ---------------- split-f16 MFMA GEMM (unchanged, passing since round 6) --------
__global__ __launch_bounds__(256, 2) void gemm_split16(
        const float* __restrict__ A, const float* __restrict__ Bm,
        const float* __restrict__ bias, float* __restrict__ C,
        int M, int N, int K, int GM, int perm) {
    __shared__ _Float16 AhS[128 * LDH];
    __shared__ _Float16 AlS[128 * LDH];
    __shared__ _Float16 BhS[128 * LDH];
    __shared__ _Float16 BlS[128 * LDH];

    int nNt = N >> 7;
    int perGroup = GM * nNt;
    int g = blockIdx.x / perGroup;
    int rix = blockIdx.x % perGroup;
    int n_t = rix / GM;
    int m_t = g * GM + (rix % GM);

    int tid = threadIdx.x;
    int srow = tid >> 1;
    int shf = tid & 1;

    const float* aptr = A + (size_t)(m_t * 128 + srow) * K + shf * 16;
    const float* bptr = Bm + (size_t)(n_t * 128 + srow) * K + shf * 16;

    int wid = tid >> 6;
    int wr = wid >> 1, wc = wid & 1;
    int lane = tid & 63;
    int fr = lane & 15;
    int ke = lane >> 4;

    f32x4 acc[4][4];
#pragma unroll
    for (int i = 0; i < 4; i++)
#pragma unroll
        for (int j = 0; j < 4; j++) acc[i][j] = (f32x4){0.f, 0.f, 0.f, 0.f};

    float4 a4[4], b4[4];
#pragma unroll
    for (int q = 0; q < 4; q++) {
        a4[q] = *(const float4*)(aptr + q * 4);
        b4[q] = *(const float4*)(bptr + q * 4);
    }

    for (int k0 = 0; k0 < K; k0 += BK) {
        __syncthreads();
#pragma unroll
        for (int q = 0; q < 4; q++) {
            half4v hh, hl;
            hh.x = (_Float16)a4[q].x; hl.x = (_Float16)(a4[q].x - (float)hh.x);
            hh.y = (_Float16)a4[q].y; hl.y = (_Float16)(a4[q].y - (float)hh.y);
            hh.z = (_Float16)a4[q].z; hl.z = (_Float16)(a4[q].z - (float)hh.z);
            hh.w = (_Float16)a4[q].w; hl.w = (_Float16)(a4[q].w - (float)hh.w);
            int o = srow * LDH + shf * 16 + q * 4;
            *(half4v*)&AhS[o] = hh;
            *(half4v*)&AlS[o] = hl;
            half4v gh, gl;
            gh.x = (_Float16)b4[q].x; gl.x = (_Float16)(b4[q].x - (float)gh.x);
            gh.y = (_Float16)b4[q].y; gl.y = (_Float16)(b4[q].y - (float)gh.y);
            gh.z = (_Float16)b4[q].z; gl.z = (_Float16)(b4[q].z - (float)gh.z);
            gh.w = (_Float16)b4[q].w; gl.w = (_Float16)(b4[q].w - (float)gh.w);
            *(half4v*)&BhS[o] = gh;
            *(half4v*)&BlS[o] = gl;
        }
        __syncthreads();

        if (k0 + BK < K) {
#pragma unroll
            for (int q = 0; q < 4; q++) {
                a4[q] = *(const float4*)(aptr + k0 + BK + q * 4);
                b4[q] = *(const float4*)(bptr + k0 + BK + q * 4);
            }
        }

        half8v ah[4], al[4], bh[4], bl[4];
#pragma unroll
        for (int i = 0; i < 4; i++) {
            int ao = (wr * 64 + i * 16 + fr) * LDH + ke * 8;
            ah[i] = *(const half8v*)&AhS[ao];
            al[i] = *(const half8v*)&AlS[ao];
            int bo = (wc * 64 + i * 16 + fr) * LDH + ke * 8;
            bh[i] = *(const half8v*)&BhS[bo];
            bl[i] = *(const half8v*)&BlS[bo];
        }
#pragma unroll
        for (int i = 0; i < 4; i++)
#pragma unroll
            for (int j = 0; j < 4; j++) {
                acc[i][j] = __builtin_amdgcn_mfma_f32_16x16x32_f16(ah[i], bh[j], acc[i][j], 0, 0, 0);
                acc[i][j] = __builtin_amdgcn_mfma_f32_16x16x32_f16(ah[i], bl[j], acc[i][j], 0, 0, 0);
                acc[i][j] = __builtin_amdgcn_mfma_f32_16x16x32_f16(al[i], bh[j], acc[i][j], 0, 0, 0);
            }
    }

#pragma unroll
    for (int j = 0; j < 4; j++) {
        int col = n_t * 128 + wc * 64 + j * 16 + fr;
        float bv = bias[col];
#pragma unroll
        for (int i = 0; i < 4; i++) {
#pragma unroll
            for (int v = 0; v < 4; v++) {
                int mrow = m_t * 128 + wr * 64 + i * 16 + 4 * ke + v;
                int orow = perm ? (((mrow & 15) << 8) | (mrow >> 4)) : mrow;
                C[(size_t)orow * N + col] = acc[i][j][v] + bv;
            }
        }
    }
}

// ---------------- agent-coherent store (bypass non-coherent L2, hit LLC) --------
__device__ __forceinline__ void store_f32_sc(float* p, float v) {
    asm volatile("global_store_dword %0, %1, off sc0 sc1" :: "v"(p), "v"(v) : "memory");
}

// ---------------- persistent GRU scan (one layer) ----------------
// 256 WGs x 256 threads, 1 block/CU (100KB LDS). WG wg owns cols [wg*4, wg*4+4).
// Thread (bg = tid>>6, kc = tid&63): 4 batches x 16 k-floats; 48 b128 ds_reads
// per step; conflict-free reduce layout red[o*65+kc].
// Barrier: hierarchical 2-hop. Arrive -> private spread flag; 8 leader blocks
// poll their 32 member flags (32 lanes x 1 dword) and post 1 of 8 spread
// gflags; everyone polls the 8 gflags with 8 lanes. Poll traffic ~2.3K line
// reads/round vs 65K in the flat all-poll (round-7/8 LLC congestion bug).
// xp[t+1] prefetch is issued BETWEEN arrive and poll so its LLC latency hides
// in the wait instead of delaying the pre-barrier vmcnt drain.
__global__ __launch_bounds__(256, 1) void gru_scan(const float* __restrict__ xp,
                                                   const float* __restrict__ Whh,
                                                   const float* __restrict__ bhh,
                                                   const float* __restrict__ h0src,
                                                   float* __restrict__ ys,
                                                   float* __restrict__ buf0,
                                                   float* __restrict__ buf1,
                                                   float* __restrict__ hid,
                                                   unsigned* __restrict__ flags,
                                                   unsigned* __restrict__ gflags,
                                                   unsigned gen_base) {
    __shared__ float w_lds[12 * 1028];      // 48.2 KB
    __shared__ float red[192 * 65];         // 49.9 KB, [o][kc] lane-consecutive
    __shared__ float sum_lds[192];
    __shared__ float bhh_lds[12];

    int wg = blockIdx.x;
    int j0 = wg * 4;
    int tid = threadIdx.x;

    for (int rr = 0; rr < 12; rr++) {
        int gate = rr >> 2, jloc = rr & 3;
        int grow = gate * FEAT + j0 + jloc;
        float4 v = ((const float4*)(Whh + (size_t)grow * FEAT))[tid];
        *(float4*)(w_lds + rr * 1028 + tid * 4) = v;
    }
    if (tid < 12) {
        int gate = tid >> 2, jloc = tid & 3;
        bhh_lds[tid] = bhh[gate * FEAT + j0 + jloc];
    }
    __syncthreads();

    int bg = tid >> 6;        // 0..3 : batch group (4 batches)
    int kc = tid & 63;        // 0..63 : k base kc*4, q-strided by 256
    int pb = tid >> 2, pjl = tid & 3, pj = j0 + pjl;   // gating map (tid<64)

    float xr = 0.f, xz = 0.f, xnv = 0.f;
    if (tid < 64) {
        const float* xpr = xp + (size_t)(0 * NB + pb) * G3;
        xr = xpr[pj]; xz = xpr[FEAT + pj]; xnv = xpr[2 * FEAT + pj];
    }

    for (int t = 0; t < NT; t++) {
        const float* hc = (t == 0) ? h0src : ((t & 1) ? buf0 : buf1);
        float* hn = (t & 1) ? buf1 : buf0;

        float hold = 0.f;
        if (tid < 64) {
            asm volatile("global_load_dword %0, %1, off sc0 sc1"
                         : "=&v"(hold) : "v"(hc + pb * FEAT + pj) : "memory");
        }

        // ---- coherent h load: 4 batches x 4 q-chunks, lane-contiguous 16B ----
        f4 h4[16];   // h4[bi*4+q]
        {
            const float* p0 = hc + (bg * 4 + 0) * FEAT + kc * 4;
            const float* p1 = hc + (bg * 4 + 1) * FEAT + kc * 4;
            const float* p2 = hc + (bg * 4 + 2) * FEAT + kc * 4;
            const float* p3 = hc + (bg * 4 + 3) * FEAT + kc * 4;
            asm volatile(
                "global_load_dwordx4 %0,  %16, off sc0 sc1\n\t"
                "global_load_dwordx4 %1,  %16, off offset:1024 sc0 sc1\n\t"
                "global_load_dwordx4 %2,  %16, off offset:2048 sc0 sc1\n\t"
                "global_load_dwordx4 %3,  %16, off offset:3072 sc0 sc1\n\t"
                "global_load_dwordx4 %4,  %17, off sc0 sc1\n\t"
                "global_load_dwordx4 %5,  %17, off offset:1024 sc0 sc1\n\t"
                "global_load_dwordx4 %6,  %17, off offset:2048 sc0 sc1\n\t"
                "global_load_dwordx4 %7,  %17, off offset:3072 sc0 sc1\n\t"
                "global_load_dwordx4 %8,  %18, off sc0 sc1\n\t"
                "global_load_dwordx4 %9,  %18, off offset:1024 sc0 sc1\n\t"
                "global_load_dwordx4 %10, %18, off offset:2048 sc0 sc1\n\t"
                "global_load_dwordx4 %11, %18, off offset:3072 sc0 sc1\n\t"
                "global_load_dwordx4 %12, %19, off sc0 sc1\n\t"
                "global_load_dwordx4 %13, %19, off offset:1024 sc0 sc1\n\t"
                "global_load_dwordx4 %14, %19, off offset:2048 sc0 sc1\n\t"
                "global_load_dwordx4 %15, %19, off offset:3072 sc0 sc1\n\t"
                "s_waitcnt vmcnt(0)"
                : "=&v"(h4[0]), "=&v"(h4[1]), "=&v"(h4[2]), "=&v"(h4[3]),
                  "=&v"(h4[4]), "=&v"(h4[5]), "=&v"(h4[6]), "=&v"(h4[7]),
                  "=&v"(h4[8]), "=&v"(h4[9]), "=&v"(h4[10]), "=&v"(h4[11]),
                  "=&v"(h4[12]), "=&v"(h4[13]), "=&v"(h4[14]), "=&v"(h4[15])
                : "v"(p0), "v"(p1), "v"(p2), "v"(p3) : "memory");
            __builtin_amdgcn_sched_barrier(0);
        }

        // ---- 12 rows x 4 batches partials; W read once per (q,row) ----
        float part[48];
#pragma unroll
        for (int i = 0; i < 48; i++) part[i] = 0.f;
#pragma unroll
        for (int q = 0; q < 4; q++) {
            int kof = q * 256 + kc * 4;
#pragma unroll
            for (int rr = 0; rr < 12; rr++) {
                f4 w = *(const f4*)&w_lds[rr * 1028 + kof];
#pragma unroll
                for (int bi = 0; bi < 4; bi++) {
                    part[rr * 4 + bi] = fmaf(h4[bi * 4 + q].x, w.x, part[rr * 4 + bi]);
                    part[rr * 4 + bi] = fmaf(h4[bi * 4 + q].y, w.y, part[rr * 4 + bi]);
                    part[rr * 4 + bi] = fmaf(h4[bi * 4 + q].z, w.z, part[rr * 4 + bi]);
                    part[rr * 4 + bi] = fmaf(h4[bi * 4 + q].w, w.w, part[rr * 4 + bi]);
                }
            }
        }
#pragma unroll
        for (int rr = 0; rr < 12; rr++)
#pragma unroll
            for (int bi = 0; bi < 4; bi++)
                red[(rr * 16 + bg * 4 + bi) * 65 + kc] = part[rr * 4 + bi];
        __syncthreads();

        if (tid < 192) {
            float s = 0.f;
#pragma unroll
            for (int q = 0; q < 64; q++) s += red[tid * 65 + q];
            sum_lds[tid] = s;
        }
        __syncthreads();

        if (tid < 64) {
            float dr = sum_lds[pjl * 16 + pb] + bhh_lds[pjl];
            float dz = sum_lds[(4 + pjl) * 16 + pb] + bhh_lds[4 + pjl];
            float dn = sum_lds[(8 + pjl) * 16 + pb] + bhh_lds[8 + pjl];
            float r = 1.f / (1.f + expf(-(xr + dr)));
            float z = 1.f / (1.f + expf(-(xz + dz)));
            float n = tanhf(xnv + r * dn);
            float hv = (1.f - z) * n + z * hold;
            store_f32_sc(hn + pb * FEAT + pj, hv);       // coherent h publish
            ys[(size_t)(t * NB + pb) * FEAT + pj] = hv;  // plain (next kernel)
            if (t == NT - 1) hid[pb * FEAT + pj] = hv;
        }

        // ================= hierarchical 2-hop barrier =================
        unsigned expected = gen_base + t + 1;
        __syncthreads();                 // compiler drains vmcnt -> h at LLC
        if (tid == 0) {
            asm volatile("global_store_dword %0, %1, off sc0 sc1"
                         :: "v"(&flags[wg * FLAG_STRIDE]), "v"(expected) : "memory");
        }
        // xp[t+1] prefetch issued inside the wait window (latency hidden)
        if (tid < 64) {
            int tn = (t + 1 < NT) ? t + 1 : t;
            const float* xpr = xp + (size_t)(tn * NB + pb) * G3;
            xr = xpr[pj]; xz = xpr[FEAT + pj]; xnv = xpr[2 * FEAT + pj];
        }
        if (wg < NGRP) {
            // leader: poll this group's 32 member flags (lanes 0..31)
            if (tid < GSZ) {
                const unsigned* fp = flags + (wg * GSZ + tid) * FLAG_STRIDE;
                unsigned v; int spins = 0;
                while (true) {
                    asm volatile("global_load_dword %0, %1, off sc0 sc1\n\t"
                                 "s_waitcnt vmcnt(0)"
                                 : "=&v"(v) : "v"(fp) : "memory");
                    if (v >= expected) break;
                    if (++spins > (1 << 20)) break;   // safety valve
                    __builtin_amdgcn_s_sleep(1);
                }
            }
            if (tid == 0) {              // wave reconverged: all 32 seen
                asm volatile("global_store_dword %0, %1, off sc0 sc1"
                             :: "v"(&gflags[wg * FLAG_STRIDE]), "v"(expected) : "memory");
            }
        }
        // everyone: wait for the 8 group flags (lanes 0..7)
        if (tid < NGRP) {
            const unsigned* gp = gflags + tid * FLAG_STRIDE;
            unsigned v; int spins = 0;
            while (true) {
                asm volatile("global_load_dword %0, %1, off sc0 sc1\n\t"
                             "s_waitcnt vmcnt(0)"
                             : "=&v"(v) : "v"(gp) : "memory");
                if (v >= expected) break;
                if (++spins > (1 << 20)) break;       // safety valve
                __builtin_amdgcn_s_sleep(1);
            }
        }
        __builtin_amdgcn_sched_barrier(0);
        __syncthreads();                 // release waves 1-3
    }
}

// ---------------- launcher ----------------
extern "C" void kernel_launch(void* const* d_in, const int* in_sizes, int n_in,
                              void* d_out, int out_size, void* d_ws, size_t ws_size,
                              hipStream_t stream) {
    const int*   x     = (const int*)d_in[0];
    const float* h0    = (const float*)d_in[1];
    const float* emb   = (const float*)d_in[2];
    const float* W_ih0 = (const float*)d_in[3];
    const float* W_hh0 = (const float*)d_in[4];
    const float* b_ih0 = (const float*)d_in[5];
    const float* b_hh0 = (const float*)d_in[6];
    const float* W_ih1 = (const float*)d_in[7];
    const float* W_hh1 = (const float*)d_in[8];
    const float* b_ih1 = (const float*)d_in[9];
    const float* b_hh1 = (const float*)d_in[10];
    const float* dec_b = (const float*)d_in[11];

    float* out = (float*)d_out;
    float* hid_out = out + (size_t)NB * NT * VOCAB;

    float* ws  = (float*)d_ws;
    float* xp  = ws;                                    // [4096][3072]
    float* xs  = xp + (size_t)4096 * 3072;              // [4096][1024] (also ys1)
    float* ys0 = xs + (size_t)4096 * 1024;              // [4096][1024]
    float* ha  = ys0 + (size_t)4096 * 1024;             // [16][1024]
    float* hb  = ha + NB * FEAT;                        // [16][1024]
    unsigned* flags  = (unsigned*)(hb + NB * FEAT);     // 256 * 32 uints (128B apart)
    unsigned* gflags = flags + NWG * FLAG_STRIDE;       // 8 * 32 uints
    float* ys1 = xs;                                    // reuse (xs dead after xp0)

    // 0. zero the barrier flags + group flags
    hipMemsetAsync((void*)flags, 0,
                   (NWG + NGRP) * FLAG_STRIDE * sizeof(unsigned), stream);

    // 1. gather
    gather_kernel<<<dim3(NT * NB), dim3(256), 0, stream>>>(x, emb, xs);

    // 2. x_proj layer 0 (split-f16 MFMA)
    gemm_split16<<<dim3((4096 / 128) * (G3 / 128)), dim3(256), 0, stream>>>(
        xs, W_ih0, b_ih0, xp, 4096, G3, FEAT, 8, 0);

    // 3. scan layer 0 (gens 1..256)
    gru_scan<<<dim3(NWG), dim3(256), 0, stream>>>(
        xp, W_hh0, b_hh0, h0, ys0, ha, hb, hid_out, flags, gflags, 0u);

    // 4. x_proj layer 1
    gemm_split16<<<dim3((4096 / 128) * (G3 / 128)), dim3(256), 0, stream>>>(
        ys0, W_ih1, b_ih1, xp, 4096, G3, FEAT, 8, 0);

    // 5. scan layer 1 (gens 257..512)
    gru_scan<<<dim3(NWG), dim3(256), 0, stream>>>(
        xp, W_hh1, b_hh1, h0 + NB * FEAT, ys1, ha, hb, hid_out + NB * FEAT,
        flags, gflags, (unsigned)NT);

    // 6. tied decoder (split-f16 MFMA, perm on C-write)
    gemm_split16<<<dim3((4096 / 128) * (VOCAB / 128)), dim3(256), 0, stream>>>(
        ys1, emb, dec_b, out, 4096, VOCAB, FEAT, 8, 1);
}